// Round 8
// baseline (1544.381 us; speedup 1.0000x reference)
//
#include <hip/hip_runtime.h>
#include <stdint.h>

// Problem constants (fixed by the reference)
#define BROWS 8192
#define DIN   768
#define DLAT  12288
#define KTOP  64

#define LO_SCALE 4096.0f      // 2^12: keeps fp16 lo-terms normal
#define LO_INV   (1.0f / 4096.0f)

// np-association model ledger: Model 1 — single sequential fmaf chain over
// all k in [0,768), bias last (see R0-R7 notes in session log).
//
// R0: k_enc_gemm -> 8-phase 256x128 pipelined schedule (total 2198 -> 1828).
// R1: k_topk -> 4-round radix-256 select + float4 I/O (total 1828 -> 1521).
// R2: barriers 8->3/tile: only -3% (502->488). Barrier count wasn't it.
// R3/R4: monolithic 1-barrier variant died twice to container infra.
// R5: 1-barrier/tile: 488->467 (-4%), MfmaUtil 46%. Pipes ADDITIVE:
//     wall/tile 3900cyc = MFMA 1862 + LDS 1536 + ~500 boundary.
// R6: cross-tile register prefetch REGRESSED (467->557, MfmaUtil 37%).
//     Post-mortem: C++ ds_reads are not pinned; the 12 prefetch reads'
//     only consumers are the loop-end rotation copies, so the scheduler
//     SANK them past H2 -> lgkmcnt(0)+BAR2 serialized them (+750cyc/tile).
//     The R6 schedule was never actually emitted.
// R7 (this round): same R6 structure + THREE sched_barrier(0) pins (rule
//     #18 / T19 fix) forcing region order:
//       BAR1 | A23 reads | SB | H1 x48 MFMA | SB | 12 prefetch reads | SB |
//       H2 x48 MFMA | lgkm(0) vmcnt BAR2
//     lgkm queue = [A23][prefetch]: H2 waits counted lgkmcnt(12) (prefetch
//     in flight under H2), lgkm(0) at BAR2 free. Bitwise-identical H.

typedef _Float16 half8 __attribute__((ext_vector_type(8)));  // 8 x fp16 (4 VGPRs)
typedef __attribute__((ext_vector_type(4))) float float4v;   // 4 x fp32 acc

typedef __attribute__((address_space(3))) void lds_void_t;
typedef __attribute__((address_space(1))) void glob_void_t;

__device__ __forceinline__ unsigned short f2h_bits(float f) {
  _Float16 h = (_Float16)f;          // RNE
  return __builtin_bit_cast(unsigned short, h);
}
__device__ __forceinline__ float h_bits_to_f(unsigned short b) {
  return (float)__builtin_bit_cast(_Float16, b);
}

// ---- x [8192,768] fp32 -> (Xh, Xl) fp16 split; lo scaled by 2^12 ----------
__global__ __launch_bounds__(256) void k_cvt_split(const float* __restrict__ in,
                                                   unsigned short* __restrict__ hi,
                                                   unsigned short* __restrict__ lo,
                                                   int n4) {
  int i = blockIdx.x * 256 + threadIdx.x;
  if (i >= n4) return;
  float4 v = ((const float4*)in)[i];
  ushort4 h, l;
  h.x = f2h_bits(v.x); l.x = f2h_bits((v.x - h_bits_to_f(h.x)) * LO_SCALE);
  h.y = f2h_bits(v.y); l.y = f2h_bits((v.y - h_bits_to_f(h.y)) * LO_SCALE);
  h.z = f2h_bits(v.z); l.z = f2h_bits((v.z - h_bits_to_f(h.z)) * LO_SCALE);
  h.w = f2h_bits(v.w); l.w = f2h_bits((v.w - h_bits_to_f(h.w)) * LO_SCALE);
  ((ushort4*)hi)[i] = h;
  ((ushort4*)lo)[i] = l;
}

// ---- W_enc [768,12288] fp32 -> Wt_hi/Wt_lo [12288,768] fp16 (transpose+split)
__global__ __launch_bounds__(256) void k_transpose_split(const float* __restrict__ W,
                                                         unsigned short* __restrict__ Wth,
                                                         unsigned short* __restrict__ Wtl) {
  __shared__ float s[32][33];
  const int n0 = blockIdx.x * 32;
  const int k0 = blockIdx.y * 32;
  const int tx = threadIdx.x, ty = threadIdx.y;  // 32 x 8
#pragma unroll
  for (int i = 0; i < 4; i++)
    s[ty + 8 * i][tx] = W[(size_t)(k0 + ty + 8 * i) * DLAT + n0 + tx];
  __syncthreads();
#pragma unroll
  for (int i = 0; i < 4; i++) {
    int nl = ty + 8 * i;
    float v = s[tx][nl];
    unsigned short h = f2h_bits(v);
    unsigned short l = f2h_bits((v - h_bits_to_f(h)) * LO_SCALE);
    size_t o = (size_t)(n0 + nl) * DIN + k0 + tx;
    Wth[o] = h;
    Wtl[o] = l;
  }
}

// ---- encoder GEMM: H = X * Wt^T + b_enc, fp16 2-term split ------------------
// 256x128 tile, 512 threads (8 waves: 4M x 2N, 64x64 per wave), BK=32.
// 3-buffer LDS rotation, counted vmcnt(6), XOR bank swizzle (both-sides),
// setprio. R7: cross-tile register prefetch + sched_barrier pins.
#define GBM 256
#define GBN 128
#define GBK 32

#define MFMA3(MI, NI, AH, AL, BH, BL)                                                        \
  acc1[MI][NI] = __builtin_amdgcn_mfma_f32_16x16x32_f16(AH, BH, acc1[MI][NI], 0, 0, 0);      \
  acc2[MI][NI] = __builtin_amdgcn_mfma_f32_16x16x32_f16(AL, BH, acc2[MI][NI], 0, 0, 0);      \
  acc2[MI][NI] = __builtin_amdgcn_mfma_f32_16x16x32_f16(AH, BL, acc2[MI][NI], 0, 0, 0);

#define CLUSTER(MI, AH, AL)                                                                  \
  MFMA3(MI, 0, AH, AL, bh0, bl0)                                                             \
  MFMA3(MI, 1, AH, AL, bh1, bl1)                                                             \
  MFMA3(MI, 2, AH, AL, bh2, bl2)                                                             \
  MFMA3(MI, 3, AH, AL, bh3, bl3)

#define STAGE1(R)                                                                            \
  __builtin_amdgcn_global_load_lds((glob_void_t*)(src[R] + kk2),                             \
                                   (lds_void_t*)(sb + loff[R]), 16, 0, 0)

__global__ __launch_bounds__(512, 2) void k_enc_gemm(const unsigned short* __restrict__ Xh,
                                                     const unsigned short* __restrict__ Xl,
                                                     const unsigned short* __restrict__ Wth,
                                                     const unsigned short* __restrict__ Wtl,
                                                     const float* __restrict__ b_enc,
                                                     float* __restrict__ H) {
  __shared__ unsigned short lds[3][24576];  // 3 x 48 KB = 144 KB

  const int tid  = threadIdx.x;
  const int lane = tid & 63;
  const int wave = tid >> 6;          // 0..7
  const int wm   = wave >> 1;         // 0..3 (M quadrant)
  const int wn   = wave & 1;          // 0..1 (N half)

  // Bijective XCD-aware swizzle: 3072 wgs, 3072/8 = 384 per XCD.
  const int wg = (blockIdx.x & 7) * 384 + (blockIdx.x >> 3);
  const int tm = wg / 96;             // 32 m-tiles
  const int tn = wg - tm * 96;        // 96 n-tiles (consecutive wgs share A-panel)
  const int m_blk = tm * GBM;
  const int n_blk = tn * GBN;

  // ---- staging setup: chunk c = wave*6+r = 1 KB = 16 rows of one stream ----
  // LDS dest is linear (global_load_lds writes base + lane*16). The bank
  // swizzle is realized by pre-swizzling the per-lane GLOBAL source quarter:
  //   physical quarter (lane&3) holds logical quarter (lane&3)^((row>>1)&3).
  const int qlog = (lane & 3) ^ ((lane >> 3) & 3);
  const unsigned short* src[6];
  int loff[6];
#pragma unroll
  for (int r = 0; r < 6; r++) {
    const int c = wave * 6 + r;
    const unsigned short* base;
    int grow;
    if (c < 16)      { base = Xh;  grow = m_blk + c * 16; }
    else if (c < 32) { base = Xl;  grow = m_blk + (c - 16) * 16; }
    else if (c < 40) { base = Wth; grow = n_blk + (c - 32) * 16; }
    else             { base = Wtl; grow = n_blk + (c - 40) * 16; }
    src[r]  = base + (size_t)(grow + (lane >> 2)) * DIN + qlog * 8;
    loff[r] = c * 512;
  }

  // ---- fragment-read offsets (ushort units), same XOR on the read side ----
  // row = <multiple of 8> + (lane&15)  =>  (row>>1)&3 == (lane>>1)&3
  const int qp   = (lane >> 4) ^ ((lane >> 1) & 3);
  const int aoff = (wm * 64 + (lane & 15)) * 32 + qp * 8;          // A-hi; +8192 for lo
  const int boff = 16384 + (wn * 64 + (lane & 15)) * 32 + qp * 8;  // B-hi; +4096 for lo

  float4v acc1[4][4];  // hi*hi
  float4v acc2[4][4];  // hi*lo + lo*hi (carries 2^12)
#pragma unroll
  for (int i = 0; i < 4; i++)
#pragma unroll
    for (int j = 0; j < 4; j++) { acc1[i][j] = (float4v)0.0f; acc2[i][j] = (float4v)0.0f; }

  // ---- prologue: stage K-tiles 0 and 1 (6 loads each per thread) ----
#pragma unroll
  for (int r = 0; r < 6; r++)
    __builtin_amdgcn_global_load_lds((glob_void_t*)(src[r]),
                                     (lds_void_t*)(&lds[0][loff[r]]), 16, 0, 0);
#pragma unroll
  for (int r = 0; r < 6; r++)
    __builtin_amdgcn_global_load_lds((glob_void_t*)(src[r] + GBK),
                                     (lds_void_t*)(&lds[1][loff[r]]), 16, 0, 0);
  asm volatile("s_waitcnt vmcnt(6)" ::: "memory");   // own tile-0 loads retired
  asm volatile("s_barrier" ::: "memory");            // tile 0 fully landed (all waves)

  const unsigned short* p_cur = lds[0];
  const unsigned short* p_nxt = lds[1];
  unsigned short*       p_stg = lds[2];

  // ---- prefetch tile 0's H1 operand set: all B frags + A mi0/mi1 ----
  half8 bh0 = *(const half8*)(p_cur + boff);
  half8 bl0 = *(const half8*)(p_cur + boff + 4096);
  half8 bh1 = *(const half8*)(p_cur + boff + 512);
  half8 bl1 = *(const half8*)(p_cur + boff + 4096 + 512);
  half8 bh2 = *(const half8*)(p_cur + boff + 1024);
  half8 bl2 = *(const half8*)(p_cur + boff + 4096 + 1024);
  half8 bh3 = *(const half8*)(p_cur + boff + 1536);
  half8 bl3 = *(const half8*)(p_cur + boff + 4096 + 1536);
  half8 pah0 = *(const half8*)(p_cur + aoff);
  half8 pal0 = *(const half8*)(p_cur + aoff + 8192);
  half8 pah1 = *(const half8*)(p_cur + aoff + 512);
  half8 pal1 = *(const half8*)(p_cur + aoff + 8192 + 512);

#pragma unroll 1
  for (int t = 0; t < 24; t++) {
    const unsigned short* lb = p_cur;
    const unsigned short* nb = p_nxt;
    unsigned short*       sb = p_stg;
    const int kk2 = t * GBK + 2 * GBK;

    // ---- stage tile t+2, then make tile t+1 visible to all waves ----
    if (t < 22) { STAGE1(0); STAGE1(1); STAGE1(2); STAGE1(3); STAGE1(4); STAGE1(5); }
    if (t < 22)       { asm volatile("s_waitcnt vmcnt(6)" ::: "memory"); }
    else if (t == 22) { asm volatile("s_waitcnt vmcnt(0)" ::: "memory"); }
    asm volatile("s_barrier" ::: "memory");   // BAR1: tile t+1 fully landed

    // ---- region 1: A mi2/mi3 reads of current tile (oldest in lgkm queue) --
    half8 ah2 = *(const half8*)(lb + aoff + 1024);
    half8 al2 = *(const half8*)(lb + aoff + 8192 + 1024);
    half8 ah3 = *(const half8*)(lb + aoff + 1536);
    half8 al3 = *(const half8*)(lb + aoff + 8192 + 1536);
    __builtin_amdgcn_sched_barrier(0);   // pin: A23 reads issue before H1

    // ---- region 2: H1 — operands already in registers, fires immediately --
    __builtin_amdgcn_s_setprio(1);
    CLUSTER(0, pah0, pal0)
    CLUSTER(1, pah1, pal1)
    __builtin_amdgcn_s_setprio(0);
    __builtin_amdgcn_sched_barrier(0);   // pin: H1 above, prefetch below

    // ---- region 3: prefetch tile t+1's H1 set from p_nxt ----
    // (t==23 reads stale data; values never used, drained by lgkmcnt.)
    half8 nbh0 = *(const half8*)(nb + boff);
    half8 nbl0 = *(const half8*)(nb + boff + 4096);
    half8 nbh1 = *(const half8*)(nb + boff + 512);
    half8 nbl1 = *(const half8*)(nb + boff + 4096 + 512);
    half8 nbh2 = *(const half8*)(nb + boff + 1024);
    half8 nbl2 = *(const half8*)(nb + boff + 4096 + 1024);
    half8 nbh3 = *(const half8*)(nb + boff + 1536);
    half8 nbl3 = *(const half8*)(nb + boff + 4096 + 1536);
    half8 nah0 = *(const half8*)(nb + aoff);
    half8 nal0 = *(const half8*)(nb + aoff + 8192);
    half8 nah1 = *(const half8*)(nb + aoff + 512);
    half8 nal1 = *(const half8*)(nb + aoff + 8192 + 512);
    __builtin_amdgcn_sched_barrier(0);   // pin: prefetch cannot sink past H2

    // ---- region 4: H2 — waits counted lgkmcnt(12) for A23 only ----
    __builtin_amdgcn_s_setprio(1);
    CLUSTER(2, ah2, al2)
    CLUSTER(3, ah3, al3)
    __builtin_amdgcn_s_setprio(0);

    // ---- BAR2: all reads drained before this buffer family is re-staged ----
    asm volatile("s_waitcnt lgkmcnt(0)" ::: "memory");
    asm volatile("s_barrier" ::: "memory");

    // rotate prefetch registers and LDS buffers
    bh0 = nbh0; bl0 = nbl0; bh1 = nbh1; bl1 = nbl1;
    bh2 = nbh2; bl2 = nbl2; bh3 = nbh3; bl3 = nbl3;
    pah0 = nah0; pal0 = nal0; pah1 = nah1; pal1 = nal1;

    const unsigned short* tmp = p_cur;
    p_cur = p_nxt;
    p_nxt = p_stg;
    p_stg = (unsigned short*)tmp;
  }

  // ---- epilogue: identical combine to previous kernel ----
  const int col   = lane & 15;
  const int rbase = (lane >> 4) * 4;
#pragma unroll
  for (int ni = 0; ni < 4; ni++) {
    const int n = n_blk + wn * 64 + ni * 16 + col;
    const float bias = b_enc[n];
#pragma unroll
    for (int mi = 0; mi < 4; mi++) {
#pragma unroll
      for (int r = 0; r < 4; r++) {
        const int m = m_blk + wm * 64 + mi * 16 + rbase + r;
        H[(size_t)m * DLAT + n] = acc1[mi][ni][r] + acc2[mi][ni][r] * LO_INV + bias;
      }
    }
  }
}

// ---- top-64 per row with np-simulated boundary arbitration -----------------
// R1: 4-round radix-256 select (wave-private LDS histograms) replaces the
// 32-round bitwise binary search. Produces the SAME cur bit pattern.
#define UMARGIN 4e-4f
#define UCAP 64
__device__ __forceinline__ float key_to_f32(unsigned k) {
  unsigned u = (k & 0x80000000u) ? (k & 0x7fffffffu) : ~k;
  return __uint_as_float(u);
}
// keys[j] (j = 4*j4+c) holds element idx = 4*tid + 1024*j4 + c of the row.
#define KIDX(J) (4 * tid + 1024 * ((J) >> 2) + ((J) & 3))

__global__ __launch_bounds__(256) void k_topk(float* __restrict__ Z,
                                              const float* __restrict__ x,
                                              const float* __restrict__ We,
                                              const float* __restrict__ b_enc,
                                              int* __restrict__ idxl,
                                              float* __restrict__ vall) {
  const int row = blockIdx.x;
  const int tid = threadIdx.x;
  const int lane = tid & 63, wid = tid >> 6;
  float* zr = Z + (size_t)row * DLAT;

  // -- load row as float4, monotone-map to sortable unsigned keys --
  unsigned keys[48];
#pragma unroll
  for (int j4 = 0; j4 < 12; j4++) {
    const float4 v4 = ((const float4*)zr)[tid + 256 * j4];
    const float vv[4] = {v4.x, v4.y, v4.z, v4.w};
#pragma unroll
    for (int c = 0; c < 4; c++) {
      const unsigned u = __float_as_uint(vv[c]);
      keys[4 * j4 + c] = (u & 0x80000000u) ? ~u : (u | 0x80000000u);
    }
  }

  __shared__ int hist[1024];          // 4 wave-private 256-bin histograms
  __shared__ unsigned s_cur;
  __shared__ int s_krem;
  __shared__ int s_nu, s_ncert, s_out;
  __shared__ int   u_idx[UCAP];
  __shared__ float u_vf[UCAP];
  __shared__ unsigned char u_sel[UCAP];

  if (tid == 0) { s_cur = 0u; s_krem = KTOP; }
  __syncthreads();

  // -- radix-256 select: 4 rounds, high byte first --
#pragma unroll
  for (int r = 0; r < 4; r++) {
    const int sh = 24 - 8 * r;
    const unsigned pre = s_cur;       // stable since trailing barrier
    hist[tid] = 0; hist[tid + 256] = 0; hist[tid + 512] = 0; hist[tid + 768] = 0;
    __syncthreads();
#pragma unroll
    for (int j = 0; j < 48; j++) {
      const unsigned k = keys[j];
      // participation: high bits match settled prefix (r=0: shift 32 of a
      // zero-extended 64-bit value is 0 -> all participate)
      if ((((unsigned long long)(k ^ pre)) >> (sh + 8)) == 0ull)
        atomicAdd(&hist[wid * 256 + ((k >> sh) & 255)], 1);
    }
    __syncthreads();
    if (wid == 0) {
      // lane l owns bins 4l..4l+3; reduce the 4 wave copies
      const int b0 = 4 * lane;
      int t0 = hist[b0]     + hist[256 + b0]     + hist[512 + b0]     + hist[768 + b0];
      int t1 = hist[b0 + 1] + hist[256 + b0 + 1] + hist[512 + b0 + 1] + hist[768 + b0 + 1];
      int t2 = hist[b0 + 2] + hist[256 + b0 + 2] + hist[512 + b0 + 2] + hist[768 + b0 + 2];
      int t3 = hist[b0 + 3] + hist[256 + b0 + 3] + hist[512 + b0 + 3] + hist[768 + b0 + 3];
      const int s3 = t3, s2 = t2 + s3, s1 = t1 + s2, s0 = t0 + s1;
      // inclusive suffix-sum of s0 across lanes (guarded shfl_down)
      int hi = s0;
#pragma unroll
      for (int off = 1; off < 64; off <<= 1) {
        const int tmp = __shfl_down(hi, off);
        if (lane + off < 64) hi += tmp;
      }
      // S(b) = count of participating keys with bin >= b
      const int krem = s_krem;
      const int S0 = hi, S1 = hi - s0 + s1, S2 = hi - s0 + s2, S3 = hi - s0 + s3;
      // max b with S(b) >= krem  (S non-increasing in b)
      int b = -1;
      if (S0 >= krem) b = b0;
      if (S1 >= krem) b = b0 + 1;
      if (S2 >= krem) b = b0 + 2;
      if (S3 >= krem) b = b0 + 3;
#pragma unroll
      for (int off = 1; off < 64; off <<= 1) b = max(b, __shfl_xor(b, off));
      if ((b >> 2) == lane) {
        const int c = b & 3;
        const int Sb = (c == 0) ? S0 : (c == 1) ? S1 : (c == 2) ? S2 : S3;
        const int tc = (c == 0) ? t0 : (c == 1) ? t1 : (c == 2) ? t2 : t3;
        s_krem = krem - (Sb - tc);    // keys strictly above bin b are settled-in
        s_cur  = pre | ((unsigned)b << sh);
      }
    }
    __syncthreads();
  }
  const unsigned cur = s_cur;         // == 64th-largest key bit pattern
  const float h64 = key_to_f32(cur);

  if (tid == 0) { s_nu = 0; s_ncert = 0; s_out = 0; }
  __syncthreads();

  // -- classify: certain (v > h64+m) / uncertain (|v-h64| <= m) / out --
  signed char uslot[48];
  int certc = 0;
#pragma unroll
  for (int j = 0; j < 48; j++) {
    const float v = key_to_f32(keys[j]);
    uslot[j] = -1;
    if (v > h64 + UMARGIN) {
      certc++;
    } else if (v >= h64 - UMARGIN) {
      int pos = atomicAdd(&s_nu, 1);
      if (pos < UCAP) {
        u_idx[pos] = KIDX(j);
        u_vf[pos]  = v;
        uslot[j] = (signed char)pos;
      }
    }
  }
  if (certc) atomicAdd(&s_ncert, certc);
  __syncthreads();

  const int nu = min(s_nu, UCAP);
  int t = KTOP - s_ncert;                 // open slots for uncertain set
  t = max(0, min(t, nu));

  if (nu > t) {
    // genuine contest: Model 1 — single sequential fp32 fmaf chain over all
    // of k (no blocking), bias added last.
    if (tid < nu) {
      const int ci = u_idx[tid];
      const float* xr = x + (size_t)row * DIN;
      float c = 0.0f;
      for (int k = 0; k < DIN; k++)
        c = fmaf(xr[k], We[(size_t)k * DLAT + ci], c);
      u_vf[tid] = c + b_enc[ci];
    }
    __syncthreads();
    // rank on sim values (no bitwise ties occur — r7 == r4 proved it)
    if (tid == 0) {
      for (int u = 0; u < nu; u++) {
        int rank = 0;
        for (int v2 = 0; v2 < nu; v2++)
          rank += (u_vf[v2] > u_vf[u]) ||
                  (u_vf[v2] == u_vf[u] && u_idx[v2] > u_idx[u]);
        u_sel[u] = (rank < t) ? 1 : 0;
      }
    }
  } else {
    // all uncertain elements are selected; approx values stand
    if (tid < nu) u_sel[tid] = 1;
  }
  __syncthreads();

  // -- final write: z row in place (float4) + compact (idx, val) lists --
#pragma unroll
  for (int j4 = 0; j4 < 12; j4++) {
    float oc[4];
#pragma unroll
    for (int c = 0; c < 4; c++) {
      const int j = 4 * j4 + c;
      const int idx = 4 * tid + 1024 * j4 + c;
      const float v = key_to_f32(keys[j]);
      bool sel = false;
      float outv = 0.0f;
      if (v > h64 + UMARGIN) {
        sel = true; outv = v;
      } else if (uslot[j] >= 0 && u_sel[(int)uslot[j]]) {
        sel = true; outv = u_vf[(int)uslot[j]];
      }
      oc[c] = sel ? outv : 0.0f;
      if (sel) {
        int s = atomicAdd(&s_out, 1);
        if (s < KTOP) {
          idxl[row * KTOP + s] = idx;
          vall[row * KTOP + s] = outv;
        }
      }
    }
    float4 o;
    o.x = oc[0]; o.y = oc[1]; o.z = oc[2]; o.w = oc[3];
    ((float4*)zr)[tid + 256 * j4] = o;
  }
}

// ---- sparse decoder: recon = z @ W_dec + b_dec (fp32) ----------------------
__global__ __launch_bounds__(192) void k_dec(const int* __restrict__ idxl,
                                             const float* __restrict__ vall,
                                             const float* __restrict__ Wd,
                                             const float* __restrict__ b_dec,
                                             float* __restrict__ R) {
  const int row = blockIdx.x;
  const int t = threadIdx.x;
  __shared__ int   sidx[KTOP];
  __shared__ float sval[KTOP];
  if (t < KTOP) {
    sidx[t] = idxl[row * KTOP + t];
    sval[t] = vall[row * KTOP + t];
  }
  __syncthreads();
  const int c = t * 4;
  float4 acc = *(const float4*)(b_dec + c);
#pragma unroll 4
  for (int j = 0; j < KTOP; j++) {
    float4 w = *(const float4*)(Wd + (size_t)sidx[j] * DIN + c);
    const float v = sval[j];
    acc.x += v * w.x;
    acc.y += v * w.y;
    acc.z += v * w.z;
    acc.w += v * w.w;
  }
  *(float4*)(R + (size_t)row * DIN + c) = acc;
}

// ----------------------------------------------------------------------------
extern "C" void kernel_launch(void* const* d_in, const int* in_sizes, int n_in,
                              void* d_out, int out_size, void* d_ws, size_t ws_size,
                              hipStream_t stream) {
  const float* x     = (const float*)d_in[0];
  const float* W_enc = (const float*)d_in[1];
  const float* b_enc = (const float*)d_in[2];
  const float* W_dec = (const float*)d_in[3];
  const float* b_dec = (const float*)d_in[4];

  float* recon = (float*)d_out;                       // [8192, 768]
  float* z     = (float*)d_out + (size_t)BROWS * DIN; // [8192, 12288] (doubles as h)

  // X fp16 split lives in the recon region (exact 25,165,824 B fit); consumed
  // by the GEMM, then overwritten by the decoder.
  unsigned short* Xh = (unsigned short*)recon;
  unsigned short* Xl = Xh + (size_t)BROWS * DIN;

  char* ws = (char*)d_ws;
  unsigned short* Wth = (unsigned short*)ws;                  // 18,874,368 B
  unsigned short* Wtl = (unsigned short*)(ws + 18874368);     // 18,874,368 B
  int*   idxl = (int*)(ws + 2 * 18874368);                    //  2,097,152 B
  float* vall = (float*)(ws + 2 * 18874368 + 2097152);        //  2,097,152 B

  k_cvt_split<<<6144, 256, 0, stream>>>(x, Xh, Xl, (BROWS * DIN) / 4);
  k_transpose_split<<<dim3(DLAT / 32, DIN / 32), dim3(32, 8), 0, stream>>>(W_enc, Wth, Wtl);
  k_enc_gemm<<<dim3(3072), dim3(512), 0, stream>>>(Xh, Xl, Wth, Wtl, b_enc, z);
  k_topk<<<BROWS, 256, 0, stream>>>(z, x, W_enc, b_enc, idxl, vall);
  k_dec<<<BROWS, 192, 0, stream>>>(idxl, vall, W_dec, b_dec, recon);
}

// Round 9
// 1431.615 us; speedup vs baseline: 1.0788x; 1.0788x over previous
//
#include <hip/hip_runtime.h>
#include <stdint.h>

// Problem constants (fixed by the reference)
#define BROWS 8192
#define DIN   768
#define DLAT  12288
#define KTOP  64

#define LO_SCALE 4096.0f      // 2^12: keeps fp16 lo-terms normal
#define LO_INV   (1.0f / 4096.0f)

// np-association model ledger: Model 1 — single sequential fmaf chain over
// all k in [0,768), bias last.
//
// R0: k_enc_gemm -> 8-phase 256x128 pipelined schedule (total 2198 -> 1828).
// R1: k_topk -> 4-round radix-256 select + float4 I/O (total 1828 -> 1521).
// R2: barriers 8->3/tile: -3% only. Barrier count wasn't the stall.
// R5: 1-barrier/tile: 488->467, MfmaUtil 46%. Pipes additive (LDS burst then
//     MFMA burst, barrier-locked waves can't skew).
// R6/R7: cross-tile register prefetch regressed (557, MfmaUtil 37%) in BOTH
//     unpinned and sched_barrier-pinned forms. VGPR_Count stuck at 124 =>
//     acc(128)+124 = 252/256: NO register room for the 48-VGPR prefetch set;
//     compiler shuffled it through AGPR copies (serializing lgkm waits).
//     Register-prefetch family is dead at this geometry. GEMM reverts to R5.
// R8 (this round): attack the ~1000us non-GEMM. k_topk (~460us vs 130us HBM
//     floor) round-0 histogram has ~8 HOT BINS (N(0,1) exponents) -> ~100M
//     same-address LDS atomics chip-wide. Replace round 0 with an atomic-free
//     descending byte PROBE (row-max byte, packed 2-byte counts, block
//     reduce). Bit-identical s_cur/s_krem; rounds 1-3 (uniform mantissa
//     digits, few participants) keep the histogram.

typedef _Float16 half8 __attribute__((ext_vector_type(8)));  // 8 x fp16 (4 VGPRs)
typedef __attribute__((ext_vector_type(4))) float float4v;   // 4 x fp32 acc

typedef __attribute__((address_space(3))) void lds_void_t;
typedef __attribute__((address_space(1))) void glob_void_t;

__device__ __forceinline__ unsigned short f2h_bits(float f) {
  _Float16 h = (_Float16)f;          // RNE
  return __builtin_bit_cast(unsigned short, h);
}
__device__ __forceinline__ float h_bits_to_f(unsigned short b) {
  return (float)__builtin_bit_cast(_Float16, b);
}

// ---- x [8192,768] fp32 -> (Xh, Xl) fp16 split; lo scaled by 2^12 ----------
__global__ __launch_bounds__(256) void k_cvt_split(const float* __restrict__ in,
                                                   unsigned short* __restrict__ hi,
                                                   unsigned short* __restrict__ lo,
                                                   int n4) {
  int i = blockIdx.x * 256 + threadIdx.x;
  if (i >= n4) return;
  float4 v = ((const float4*)in)[i];
  ushort4 h, l;
  h.x = f2h_bits(v.x); l.x = f2h_bits((v.x - h_bits_to_f(h.x)) * LO_SCALE);
  h.y = f2h_bits(v.y); l.y = f2h_bits((v.y - h_bits_to_f(h.y)) * LO_SCALE);
  h.z = f2h_bits(v.z); l.z = f2h_bits((v.z - h_bits_to_f(h.z)) * LO_SCALE);
  h.w = f2h_bits(v.w); l.w = f2h_bits((v.w - h_bits_to_f(h.w)) * LO_SCALE);
  ((ushort4*)hi)[i] = h;
  ((ushort4*)lo)[i] = l;
}

// ---- W_enc [768,12288] fp32 -> Wt_hi/Wt_lo [12288,768] fp16 (transpose+split)
__global__ __launch_bounds__(256) void k_transpose_split(const float* __restrict__ W,
                                                         unsigned short* __restrict__ Wth,
                                                         unsigned short* __restrict__ Wtl) {
  __shared__ float s[32][33];
  const int n0 = blockIdx.x * 32;
  const int k0 = blockIdx.y * 32;
  const int tx = threadIdx.x, ty = threadIdx.y;  // 32 x 8
#pragma unroll
  for (int i = 0; i < 4; i++)
    s[ty + 8 * i][tx] = W[(size_t)(k0 + ty + 8 * i) * DLAT + n0 + tx];
  __syncthreads();
#pragma unroll
  for (int i = 0; i < 4; i++) {
    int nl = ty + 8 * i;
    float v = s[tx][nl];
    unsigned short h = f2h_bits(v);
    unsigned short l = f2h_bits((v - h_bits_to_f(h)) * LO_SCALE);
    size_t o = (size_t)(n0 + nl) * DIN + k0 + tx;
    Wth[o] = h;
    Wtl[o] = l;
  }
}

// ---- encoder GEMM: H = X * Wt^T + b_enc, fp16 2-term split ------------------
// R5 configuration (best measured: 467us, MfmaUtil 46%): 256x128 tile, 512
// threads (8 waves: 4M x 2N), BK=32, 3-buffer LDS rotation, counted vmcnt(6),
// XOR bank swizzle (both-sides), setprio, ONE barrier per K-tile.
#define GBM 256
#define GBN 128
#define GBK 32

#define MFMA12(MI, AH, AL)                                                                   \
  do {                                                                                       \
    _Pragma("unroll") for (int ni = 0; ni < 4; ni++) {                                       \
      acc1[MI][ni] = __builtin_amdgcn_mfma_f32_16x16x32_f16(AH, bh[ni], acc1[MI][ni], 0, 0, 0); \
      acc2[MI][ni] = __builtin_amdgcn_mfma_f32_16x16x32_f16(AL, bh[ni], acc2[MI][ni], 0, 0, 0); \
      acc2[MI][ni] = __builtin_amdgcn_mfma_f32_16x16x32_f16(AH, bl[ni], acc2[MI][ni], 0, 0, 0); \
    }                                                                                        \
  } while (0)

#define STAGE1(R)                                                                            \
  __builtin_amdgcn_global_load_lds((glob_void_t*)(src[R] + kk2),                             \
                                   (lds_void_t*)(sb + loff[R]), 16, 0, 0)

__global__ __launch_bounds__(512, 2) void k_enc_gemm(const unsigned short* __restrict__ Xh,
                                                     const unsigned short* __restrict__ Xl,
                                                     const unsigned short* __restrict__ Wth,
                                                     const unsigned short* __restrict__ Wtl,
                                                     const float* __restrict__ b_enc,
                                                     float* __restrict__ H) {
  __shared__ unsigned short lds[3][24576];  // 3 x 48 KB = 144 KB

  const int tid  = threadIdx.x;
  const int lane = tid & 63;
  const int wave = tid >> 6;          // 0..7
  const int wm   = wave >> 1;         // 0..3 (M quadrant)
  const int wn   = wave & 1;          // 0..1 (N half)

  // Bijective XCD-aware swizzle: 3072 wgs, 3072/8 = 384 per XCD.
  const int wg = (blockIdx.x & 7) * 384 + (blockIdx.x >> 3);
  const int tm = wg / 96;             // 32 m-tiles
  const int tn = wg - tm * 96;        // 96 n-tiles (consecutive wgs share A-panel)
  const int m_blk = tm * GBM;
  const int n_blk = tn * GBN;

  // ---- staging setup: chunk c = wave*6+r = 1 KB = 16 rows of one stream ----
  const int qlog = (lane & 3) ^ ((lane >> 3) & 3);
  const unsigned short* src[6];
  int loff[6];
#pragma unroll
  for (int r = 0; r < 6; r++) {
    const int c = wave * 6 + r;
    const unsigned short* base;
    int grow;
    if (c < 16)      { base = Xh;  grow = m_blk + c * 16; }
    else if (c < 32) { base = Xl;  grow = m_blk + (c - 16) * 16; }
    else if (c < 40) { base = Wth; grow = n_blk + (c - 32) * 16; }
    else             { base = Wtl; grow = n_blk + (c - 40) * 16; }
    src[r]  = base + (size_t)(grow + (lane >> 2)) * DIN + qlog * 8;
    loff[r] = c * 512;
  }

  // ---- fragment-read offsets (ushort units), same XOR on the read side ----
  const int qp   = (lane >> 4) ^ ((lane >> 1) & 3);
  const int aoff = (wm * 64 + (lane & 15)) * 32 + qp * 8;          // A-hi; +8192 for lo
  const int boff = 16384 + (wn * 64 + (lane & 15)) * 32 + qp * 8;  // B-hi; +4096 for lo

  float4v acc1[4][4];  // hi*hi
  float4v acc2[4][4];  // hi*lo + lo*hi (carries 2^12)
#pragma unroll
  for (int i = 0; i < 4; i++)
#pragma unroll
    for (int j = 0; j < 4; j++) { acc1[i][j] = (float4v)0.0f; acc2[i][j] = (float4v)0.0f; }

  // ---- prologue: stage K-tiles 0 and 1 (6 loads each per thread) ----
#pragma unroll
  for (int r = 0; r < 6; r++)
    __builtin_amdgcn_global_load_lds((glob_void_t*)(src[r]),
                                     (lds_void_t*)(&lds[0][loff[r]]), 16, 0, 0);
#pragma unroll
  for (int r = 0; r < 6; r++)
    __builtin_amdgcn_global_load_lds((glob_void_t*)(src[r] + GBK),
                                     (lds_void_t*)(&lds[1][loff[r]]), 16, 0, 0);
  asm volatile("s_waitcnt vmcnt(6)" ::: "memory");   // tile 0 landed (tile 1 in flight)
  asm volatile("s_barrier" ::: "memory");

  const unsigned short* p_cur = lds[0];
  const unsigned short* p_nxt = lds[1];
  unsigned short*       p_stg = lds[2];

#pragma unroll 1
  for (int t = 0; t < 24; t++) {
    const unsigned short* lb = p_cur;
    unsigned short*       sb = p_stg;
    const int kk2 = t * GBK + 2 * GBK;
    const bool do_stage = (t < 22);

    half8 bh[4], bl[4], ah0, al0, ah1, al1;

    // -------- half 1: B-frags + A mi0/mi1 || stage 3 -> 24 MFMA (no barrier)
#pragma unroll
    for (int ni = 0; ni < 4; ni++) {
      bh[ni] = *(const half8*)(lb + boff + ni * 512);
      bl[ni] = *(const half8*)(lb + boff + 4096 + ni * 512);
    }
    ah0 = *(const half8*)(lb + aoff);
    al0 = *(const half8*)(lb + aoff + 8192);
    ah1 = *(const half8*)(lb + aoff + 512);
    al1 = *(const half8*)(lb + aoff + 8192 + 512);
    if (do_stage) { STAGE1(0); STAGE1(1); STAGE1(2); }
    __builtin_amdgcn_s_setprio(1);
    MFMA12(0, ah0, al0);
    MFMA12(1, ah1, al1);
    __builtin_amdgcn_s_setprio(0);

    // -------- half 2: A mi2/mi3 || stage 3 -> 24 MFMA (no barrier) ----------
    ah0 = *(const half8*)(lb + aoff + 1024);
    al0 = *(const half8*)(lb + aoff + 8192 + 1024);
    ah1 = *(const half8*)(lb + aoff + 1536);
    al1 = *(const half8*)(lb + aoff + 8192 + 1536);
    if (do_stage) { STAGE1(3); STAGE1(4); STAGE1(5); }
    __builtin_amdgcn_s_setprio(1);
    MFMA12(2, ah0, al0);
    MFMA12(3, ah1, al1);
    __builtin_amdgcn_s_setprio(0);

    // -------- tile boundary: the ONLY barrier per tile ----------------------
    asm volatile("s_waitcnt lgkmcnt(0)" ::: "memory");
    if (t < 22)       { asm volatile("s_waitcnt vmcnt(6)" ::: "memory"); }
    else if (t == 22) { asm volatile("s_waitcnt vmcnt(0)" ::: "memory"); }
    asm volatile("s_barrier" ::: "memory");

    const unsigned short* tmp = p_cur;
    p_cur = p_nxt;
    p_nxt = p_stg;
    p_stg = (unsigned short*)tmp;
  }

  // ---- epilogue: identical combine to previous kernel ----
  const int col   = lane & 15;
  const int rbase = (lane >> 4) * 4;
#pragma unroll
  for (int ni = 0; ni < 4; ni++) {
    const int n = n_blk + wn * 64 + ni * 16 + col;
    const float bias = b_enc[n];
#pragma unroll
    for (int mi = 0; mi < 4; mi++) {
#pragma unroll
      for (int r = 0; r < 4; r++) {
        const int m = m_blk + wm * 64 + mi * 16 + rbase + r;
        H[(size_t)m * DLAT + n] = acc1[mi][ni][r] + acc2[mi][ni][r] * LO_INV + bias;
      }
    }
  }
}

// ---- top-64 per row with np-simulated boundary arbitration -----------------
// R1: radix-256 select. R8: round 0 replaced by atomic-free descending byte
// probe (bit-identical s_cur/s_krem); rounds 1-3 keep the histogram.
#define UMARGIN 4e-4f
#define UCAP 64
__device__ __forceinline__ float key_to_f32(unsigned k) {
  unsigned u = (k & 0x80000000u) ? (k & 0x7fffffffu) : ~k;
  return __uint_as_float(u);
}
// keys[j] (j = 4*j4+c) holds element idx = 4*tid + 1024*j4 + c of the row.
#define KIDX(J) (4 * tid + 1024 * ((J) >> 2) + ((J) & 3))

__global__ __launch_bounds__(256) void k_topk(float* __restrict__ Z,
                                              const float* __restrict__ x,
                                              const float* __restrict__ We,
                                              const float* __restrict__ b_enc,
                                              int* __restrict__ idxl,
                                              float* __restrict__ vall) {
  const int row = blockIdx.x;
  const int tid = threadIdx.x;
  const int lane = tid & 63, wid = tid >> 6;
  float* zr = Z + (size_t)row * DLAT;

  // -- load row as float4, monotone-map to sortable unsigned keys --
  unsigned keys[48];
#pragma unroll
  for (int j4 = 0; j4 < 12; j4++) {
    const float4 v4 = ((const float4*)zr)[tid + 256 * j4];
    const float vv[4] = {v4.x, v4.y, v4.z, v4.w};
#pragma unroll
    for (int c = 0; c < 4; c++) {
      const unsigned u = __float_as_uint(vv[c]);
      keys[4 * j4 + c] = (u & 0x80000000u) ? ~u : (u | 0x80000000u);
    }
  }

  __shared__ int hist[1024];          // 4 wave-private 256-bin histograms (rounds 1-3)
  __shared__ unsigned wmax[4];
  __shared__ unsigned s_kmax;
  __shared__ unsigned s_cur;
  __shared__ int wsum[4];
  __shared__ int s_total;
  __shared__ int s_krem;
  __shared__ int s_nu, s_ncert, s_out;
  __shared__ int   u_idx[UCAP];
  __shared__ float u_vf[UCAP];
  __shared__ unsigned char u_sel[UCAP];

  // ===== round 0 replacement: descending byte probe (no atomics) =====
  // (a) row max key
  unsigned kmax = 0;
#pragma unroll
  for (int j = 0; j < 48; j++) kmax = max(kmax, keys[j]);
#pragma unroll
  for (int off = 32; off > 0; off >>= 1) {
    const unsigned tmp = (unsigned)__shfl_xor((int)kmax, off);
    kmax = max(kmax, tmp);
  }
  if (lane == 0) wmax[wid] = kmax;
  __syncthreads();
  if (tid == 0)
    s_kmax = max(max(wmax[0], wmax[1]), max(wmax[2], wmax[3]));
  __syncthreads();

  // (b) probe bytes B, B-1, B-2, ... two at a time (packed counts).
  // Invariant: cum = #keys with top byte > b (uniform across threads).
  int b = (int)(s_kmax >> 24);
  int cum = 0;
  int bsel = 0, krem0 = KTOP;
#pragma unroll 1
  for (;;) {
    int c = 0;
#pragma unroll
    for (int j = 0; j < 48; j++) {
      const int by = (int)(keys[j] >> 24);
      c += (by == b) ? 0x10000 : 0;
      c += (by == b - 1) ? 1 : 0;
    }
#pragma unroll
    for (int off = 32; off > 0; off >>= 1) c += __shfl_down(c, off);
    if (lane == 0) wsum[wid] = c;
    __syncthreads();
    if (tid == 0) s_total = wsum[0] + wsum[1] + wsum[2] + wsum[3];
    __syncthreads();
    const int chi = s_total >> 16;          // count(byte == b)
    const int clo = s_total & 0xffff;       // count(byte == b-1)
    if (cum + chi >= KTOP) { bsel = b;     krem0 = KTOP - cum;        break; }
    if (cum + chi + clo >= KTOP) { bsel = b - 1; krem0 = KTOP - cum - chi; break; }
    cum += chi + clo;
    b -= 2;
    if (b < 0) { bsel = 0; krem0 = KTOP - cum; break; }  // unreachable safety
  }
  if (tid == 0) { s_cur = (unsigned)bsel << 24; s_krem = krem0; }
  __syncthreads();

  // ===== rounds 1-3: radix-256 histogram refinement (few participants) =====
#pragma unroll
  for (int r = 1; r < 4; r++) {
    const int sh = 24 - 8 * r;
    const unsigned pre = s_cur;       // stable since trailing barrier
    hist[tid] = 0; hist[tid + 256] = 0; hist[tid + 512] = 0; hist[tid + 768] = 0;
    __syncthreads();
#pragma unroll
    for (int j = 0; j < 48; j++) {
      const unsigned k = keys[j];
      // participation: high bits match settled prefix
      if ((((unsigned long long)(k ^ pre)) >> (sh + 8)) == 0ull)
        atomicAdd(&hist[wid * 256 + ((k >> sh) & 255)], 1);
    }
    __syncthreads();
    if (wid == 0) {
      // lane l owns bins 4l..4l+3; reduce the 4 wave copies
      const int b0 = 4 * lane;
      int t0 = hist[b0]     + hist[256 + b0]     + hist[512 + b0]     + hist[768 + b0];
      int t1 = hist[b0 + 1] + hist[256 + b0 + 1] + hist[512 + b0 + 1] + hist[768 + b0 + 1];
      int t2 = hist[b0 + 2] + hist[256 + b0 + 2] + hist[512 + b0 + 2] + hist[768 + b0 + 2];
      int t3 = hist[b0 + 3] + hist[256 + b0 + 3] + hist[512 + b0 + 3] + hist[768 + b0 + 3];
      const int s3 = t3, s2 = t2 + s3, s1 = t1 + s2, s0 = t0 + s1;
      // inclusive suffix-sum of s0 across lanes (guarded shfl_down)
      int hi = s0;
#pragma unroll
      for (int off = 1; off < 64; off <<= 1) {
        const int tmp = __shfl_down(hi, off);
        if (lane + off < 64) hi += tmp;
      }
      // S(bin) = count of participating keys with bin >= b
      const int krem = s_krem;
      const int S0 = hi, S1 = hi - s0 + s1, S2 = hi - s0 + s2, S3 = hi - s0 + s3;
      int bb = -1;
      if (S0 >= krem) bb = b0;
      if (S1 >= krem) bb = b0 + 1;
      if (S2 >= krem) bb = b0 + 2;
      if (S3 >= krem) bb = b0 + 3;
#pragma unroll
      for (int off = 1; off < 64; off <<= 1) bb = max(bb, __shfl_xor(bb, off));
      if ((bb >> 2) == lane) {
        const int c = bb & 3;
        const int Sb = (c == 0) ? S0 : (c == 1) ? S1 : (c == 2) ? S2 : S3;
        const int tc = (c == 0) ? t0 : (c == 1) ? t1 : (c == 2) ? t2 : t3;
        s_krem = krem - (Sb - tc);    // keys strictly above bin bb are settled-in
        s_cur  = pre | ((unsigned)bb << sh);
      }
    }
    __syncthreads();
  }
  const unsigned cur = s_cur;         // == 64th-largest key bit pattern
  const float h64 = key_to_f32(cur);

  if (tid == 0) { s_nu = 0; s_ncert = 0; s_out = 0; }
  __syncthreads();

  // -- classify: certain (v > h64+m) / uncertain (|v-h64| <= m) / out --
  signed char uslot[48];
  int certc = 0;
#pragma unroll
  for (int j = 0; j < 48; j++) {
    const float v = key_to_f32(keys[j]);
    uslot[j] = -1;
    if (v > h64 + UMARGIN) {
      certc++;
    } else if (v >= h64 - UMARGIN) {
      int pos = atomicAdd(&s_nu, 1);
      if (pos < UCAP) {
        u_idx[pos] = KIDX(j);
        u_vf[pos]  = v;
        uslot[j] = (signed char)pos;
      }
    }
  }
  if (certc) atomicAdd(&s_ncert, certc);
  __syncthreads();

  const int nu = min(s_nu, UCAP);
  int t = KTOP - s_ncert;                 // open slots for uncertain set
  t = max(0, min(t, nu));

  if (nu > t) {
    // genuine contest: Model 1 — single sequential fp32 fmaf chain over all
    // of k (no blocking), bias added last.
    if (tid < nu) {
      const int ci = u_idx[tid];
      const float* xr = x + (size_t)row * DIN;
      float c = 0.0f;
      for (int k = 0; k < DIN; k++)
        c = fmaf(xr[k], We[(size_t)k * DLAT + ci], c);
      u_vf[tid] = c + b_enc[ci];
    }
    __syncthreads();
    // rank on sim values (no bitwise ties occur — r7 == r4 proved it)
    if (tid == 0) {
      for (int u = 0; u < nu; u++) {
        int rank = 0;
        for (int v2 = 0; v2 < nu; v2++)
          rank += (u_vf[v2] > u_vf[u]) ||
                  (u_vf[v2] == u_vf[u] && u_idx[v2] > u_idx[u]);
        u_sel[u] = (rank < t) ? 1 : 0;
      }
    }
  } else {
    // all uncertain elements are selected; approx values stand
    if (tid < nu) u_sel[tid] = 1;
  }
  __syncthreads();

  // -- final write: z row in place (float4) + compact (idx, val) lists --
#pragma unroll
  for (int j4 = 0; j4 < 12; j4++) {
    float oc[4];
#pragma unroll
    for (int c = 0; c < 4; c++) {
      const int j = 4 * j4 + c;
      const int idx = 4 * tid + 1024 * j4 + c;
      const float v = key_to_f32(keys[j]);
      bool sel = false;
      float outv = 0.0f;
      if (v > h64 + UMARGIN) {
        sel = true; outv = v;
      } else if (uslot[j] >= 0 && u_sel[(int)uslot[j]]) {
        sel = true; outv = u_vf[(int)uslot[j]];
      }
      oc[c] = sel ? outv : 0.0f;
      if (sel) {
        int s = atomicAdd(&s_out, 1);
        if (s < KTOP) {
          idxl[row * KTOP + s] = idx;
          vall[row * KTOP + s] = outv;
        }
      }
    }
    float4 o;
    o.x = oc[0]; o.y = oc[1]; o.z = oc[2]; o.w = oc[3];
    ((float4*)zr)[tid + 256 * j4] = o;
  }
}

// ---- sparse decoder: recon = z @ W_dec + b_dec (fp32) ----------------------
__global__ __launch_bounds__(192) void k_dec(const int* __restrict__ idxl,
                                             const float* __restrict__ vall,
                                             const float* __restrict__ Wd,
                                             const float* __restrict__ b_dec,
                                             float* __restrict__ R) {
  const int row = blockIdx.x;
  const int t = threadIdx.x;
  __shared__ int   sidx[KTOP];
  __shared__ float sval[KTOP];
  if (t < KTOP) {
    sidx[t] = idxl[row * KTOP + t];
    sval[t] = vall[row * KTOP + t];
  }
  __syncthreads();
  const int c = t * 4;
  float4 acc = *(const float4*)(b_dec + c);
#pragma unroll 4
  for (int j = 0; j < KTOP; j++) {
    float4 w = *(const float4*)(Wd + (size_t)sidx[j] * DIN + c);
    const float v = sval[j];
    acc.x += v * w.x;
    acc.y += v * w.y;
    acc.z += v * w.z;
    acc.w += v * w.w;
  }
  *(float4*)(R + (size_t)row * DIN + c) = acc;
}

// ----------------------------------------------------------------------------
extern "C" void kernel_launch(void* const* d_in, const int* in_sizes, int n_in,
                              void* d_out, int out_size, void* d_ws, size_t ws_size,
                              hipStream_t stream) {
  const float* x     = (const float*)d_in[0];
  const float* W_enc = (const float*)d_in[1];
  const float* b_enc = (const float*)d_in[2];
  const float* W_dec = (const float*)d_in[3];
  const float* b_dec = (const float*)d_in[4];

  float* recon = (float*)d_out;                       // [8192, 768]
  float* z     = (float*)d_out + (size_t)BROWS * DIN; // [8192, 12288] (doubles as h)

  // X fp16 split lives in the recon region (exact 25,165,824 B fit); consumed
  // by the GEMM, then overwritten by the decoder.
  unsigned short* Xh = (unsigned short*)recon;
  unsigned short* Xl = Xh + (size_t)BROWS * DIN;

  char* ws = (char*)d_ws;
  unsigned short* Wth = (unsigned short*)ws;                  // 18,874,368 B
  unsigned short* Wtl = (unsigned short*)(ws + 18874368);     // 18,874,368 B
  int*   idxl = (int*)(ws + 2 * 18874368);                    //  2,097,152 B
  float* vall = (float*)(ws + 2 * 18874368 + 2097152);        //  2,097,152 B

  k_cvt_split<<<6144, 256, 0, stream>>>(x, Xh, Xl, (BROWS * DIN) / 4);
  k_transpose_split<<<dim3(DLAT / 32, DIN / 32), dim3(32, 8), 0, stream>>>(W_enc, Wth, Wtl);
  k_enc_gemm<<<dim3(3072), dim3(512), 0, stream>>>(Xh, Xl, Wth, Wtl, b_enc, z);
  k_topk<<<BROWS, 256, 0, stream>>>(z, x, W_enc, b_enc, idxl, vall);
  k_dec<<<BROWS, 192, 0, stream>>>(idxl, vall, W_dec, b_dec, recon);
}